// Round 1
// baseline (521.880 us; speedup 1.0000x reference)
//
#include <hip/hip_runtime.h>
#include <math.h>

#define L_MAX 3
#define RCUT 5.0f
#define NB 8
#define NCH 16
#define KDIM 64
#define LMDIM 16   // sum (2l+1), l=0..3

// ---------------- compile-time Clebsch-Gordan (mirrors reference _real_cg) ----------------
struct CD { double re; double im; };
struct UMat { CD m[7][7]; };
struct CGT { float v[7][7][7]; };

constexpr double cfact(int n){ double r=1.0; for(int i=2;i<=n;++i) r*=(double)i; return r; }
constexpr double cfabs(double x){ return x<0.0 ? -x : x; }
constexpr double csqrt_(double x){
  if (x<=0.0) return 0.0;
  double g = x>1.0 ? x : 1.0;
  for (int i=0;i<100;++i) g = 0.5*(g + x/g);
  return g;
}
constexpr double clebsch(int j1,int m1,int j2,int m2,int J,int M){
  if (m1+m2!=M) return 0.0;
  int ad = j1-j2; if (ad<0) ad=-ad;
  if (J<ad || J>j1+j2) return 0.0;
  double pref = csqrt_((2.0*J+1.0)*cfact(J+j1-j2)*cfact(J-j1+j2)*cfact(j1+j2-J)/cfact(j1+j2+J+1));
  pref *= csqrt_(cfact(J+M)*cfact(J-M)*cfact(j1-m1)*cfact(j1+m1)*cfact(j2-m2)*cfact(j2+m2));
  double s=0.0;
  for (int k=0;k<=j1+j2-J;++k){
    int d0=k,d1=j1+j2-J-k,d2=j1-m1-k,d3=j2+m2-k,d4=J-j2+m1+k,d5=J-j1-m2+k;
    if (d0<0||d1<0||d2<0||d3<0||d4<0||d5<0) continue;
    double den = cfact(d0)*cfact(d1)*cfact(d2)*cfact(d3)*cfact(d4)*cfact(d5);
    s += ((k&1)? -1.0:1.0)/den;
  }
  return pref*s;
}
constexpr UMat u_real(int l){
  UMat U{};
  U.m[l][l] = CD{1.0, 0.0};
  double is2 = csqrt_(0.5);
  for (int mm=1; mm<=l; ++mm){
    double sgn = (mm&1)? -1.0: 1.0;
    U.m[l+mm][l+mm] = CD{sgn*is2, 0.0};
    U.m[l+mm][l-mm] = CD{is2, 0.0};
    U.m[l-mm][l-mm] = CD{0.0, is2};
    U.m[l-mm][l+mm] = CD{0.0, -sgn*is2};
  }
  return U;
}
constexpr CGT real_cg(int l1,int l2,int L){
  double Cc[7][7][7] = {};
  for (int m1=-l1;m1<=l1;++m1)
    for (int m2=-l2;m2<=l2;++m2){
      int M=m1+m2;
      if (M>=-L && M<=L) Cc[l1+m1][l2+m2][L+M] = clebsch(l1,m1,l2,m2,L,M);
    }
  UMat U1=u_real(l1), U2=u_real(l2), U3=u_real(L);
  double Tre[7][7][7]={}, Tim[7][7][7]={};
  for (int a=0;a<2*l1+1;++a)
   for (int m=0;m<2*l1+1;++m){
     CD u1=U1.m[a][m];
     if (u1.re==0.0 && u1.im==0.0) continue;
     for (int b=0;b<2*l2+1;++b)
      for (int n=0;n<2*l2+1;++n){
        CD u2=U2.m[b][n];
        if (u2.re==0.0 && u2.im==0.0) continue;
        CD u12 = CD{u1.re*u2.re-u1.im*u2.im, u1.re*u2.im+u1.im*u2.re};
        for (int c=0;c<2*L+1;++c)
         for (int o=0;o<2*L+1;++o){
           CD u3=U3.m[c][o];
           if (u3.re==0.0 && u3.im==0.0) continue;
           double cc=Cc[m][n][o];
           if (cc==0.0) continue;
           double tr = u12.re*u3.re + u12.im*u3.im;   // u12 * conj(u3)
           double ti = u12.im*u3.re - u12.re*u3.im;
           Tre[a][b][c] += tr*cc;
           Tim[a][b][c] += ti*cc;
         }
      }
   }
  double sre=0.0, sim=0.0;
  for (int a=0;a<2*l1+1;++a) for (int b=0;b<2*l2+1;++b) for (int c=0;c<2*L+1;++c){
    sre += cfabs(Tre[a][b][c]); sim += cfabs(Tim[a][b][c]);
  }
  CGT out{};
  bool ure = (sre>=sim);
  for (int a=0;a<2*l1+1;++a) for (int b=0;b<2*l2+1;++b) for (int c=0;c<2*L+1;++c)
    out.v[a][b][c] = (float)(ure? Tre[a][b][c] : Tim[a][b][c]);
  return out;
}

// contraction: g[L*L+m] += C[i][j][m] * f1[l1*l1+i] * f2[l2*l2+j]
template<int l1,int l2,int L>
__device__ __forceinline__ void cg_contract(const float* __restrict__ f1,
                                            const float* __restrict__ f2,
                                            float* __restrict__ g){
  constexpr CGT cg = real_cg(l1,l2,L);
  #pragma unroll
  for (int i=0;i<2*l1+1;++i)
  #pragma unroll
  for (int j=0;j<2*l2+1;++j)
  #pragma unroll
  for (int m=0;m<2*L+1;++m){
    float c = cg.v[i][j][m];
    if (c != 0.0f) g[L*L+m] += c * f1[l1*l1+i] * f2[l2*l2+j];
  }
}

#define FOR_ALL_CG(X) \
  X(0,0,0) X(0,1,1) X(1,0,1) X(0,2,2) X(2,0,2) X(0,3,3) X(3,0,3) \
  X(1,1,0) X(1,1,1) X(1,1,2) \
  X(1,2,1) X(1,2,2) X(1,2,3) X(2,1,1) X(2,1,2) X(2,1,3) \
  X(1,3,2) X(1,3,3) X(3,1,2) X(3,1,3) \
  X(2,2,0) X(2,2,1) X(2,2,2) X(2,2,3) \
  X(2,3,1) X(2,3,2) X(2,3,3) X(3,2,1) X(3,2,2) X(3,2,3) \
  X(3,3,0) X(3,3,1) X(3,3,2) X(3,3,3)

__device__ __forceinline__ void all_contract(const float* __restrict__ f1,
                                             const float* __restrict__ f2,
                                             float* __restrict__ g){
#define XCG(a,b,c) cg_contract<a,b,c>(f1, f2, g);
  FOR_ALL_CG(XCG)
#undef XCG
}

// ---------------- geometry helpers ----------------
__device__ __forceinline__ void compute_sh(float x, float y, float z, float* sh){
  sh[0]  = 0.28209479177387814f;
  sh[1]  = 0.4886025119029199f*y;
  sh[2]  = 0.4886025119029199f*z;
  sh[3]  = 0.4886025119029199f*x;
  sh[4]  = 1.0925484305920792f*x*y;
  sh[5]  = 1.0925484305920792f*y*z;
  sh[6]  = 0.31539156525252005f*(3.0f*z*z-1.0f);
  sh[7]  = 1.0925484305920792f*x*z;
  sh[8]  = 0.5462742152960396f*(x*x-y*y);
  sh[9]  = 0.5900435899266435f*y*(3.0f*x*x-y*y);
  sh[10] = 2.890611442640554f*x*y*z;
  sh[11] = 0.4570457994644658f*y*(5.0f*z*z-1.0f);
  sh[12] = 0.3731763325901154f*z*(5.0f*z*z-3.0f);
  sh[13] = 0.4570457994644658f*x*(5.0f*z*z-1.0f);
  sh[14] = 1.445305721320277f*z*(x*x-y*y);
  sh[15] = 0.5900435899266435f*x*(x*x-3.0f*y*y);
}

// returns true if edge active (d < RC); fills sh[16], b[8]
__device__ __forceinline__ bool edge_geom(const float* __restrict__ pos, int s, int r,
                                          float* sh, float* b){
  float dx = pos[r*3+0]-pos[s*3+0];
  float dy = pos[r*3+1]-pos[s*3+1];
  float dz = pos[r*3+2]-pos[s*3+2];
  float d  = sqrtf(dx*dx+dy*dy+dz*dz + 1e-12f);
  if (d >= RCUT) return false;
  float inv_d = 1.0f/d;
  compute_sh(dx*inv_d, dy*inv_d, dz*inv_d, sh);
  float fc = 0.5f*(cosf(d*(3.14159265358979323846f/RCUT))+1.0f);
  #pragma unroll
  for (int q=0;q<NB;++q){
    float t = (d - (float)((double)q*(5.0/7.0))) * 1.6f;  // /sigma, sigma=0.625
    b[q] = expf(-0.5f*t*t)*fc;
  }
  return true;
}

// ---------------- kernel 1: edges -> feats (first message pass) ----------------
__global__ __launch_bounds__(256) void k1_edge_feats(
    const float* __restrict__ pos, const float* __restrict__ emb,
    const float* __restrict__ Winv, const int* __restrict__ species,
    const int* __restrict__ senders, const int* __restrict__ recv,
    float* __restrict__ feats, int E)
{
  int e = blockIdx.x*4 + (threadIdx.x>>6);
  if (e >= E) return;
  int lane = threadIdx.x & 63;
  int s = senders[e], r = recv[e];
  float sh[16], b[8];
  if (!edge_geom(pos, s, r, sh, b)) return;
  // R[l][n] = sum_q b[q] * Winv[l][q][n]
  float R[4][4];
  #pragma unroll
  for (int l=0;l<4;++l)
    #pragma unroll
    for (int n=0;n<4;++n){
      float acc=0.0f;
      #pragma unroll
      for (int q=0;q<NB;++q) acc += b[q]*Winv[l*32+q*4+n];
      R[l][n]=acc;
    }
  int n = lane>>4, c = lane&15;
  float xc = emb[species[s]*NCH + c];
  float tl[4];
  #pragma unroll
  for (int l=0;l<4;++l) tl[l] = 0.5f * xc * R[l][n];   // MP_SCALING
  float* fr = feats + (size_t)r*(LMDIM*KDIM) + lane;
  #pragma unroll
  for (int lm=0; lm<LMDIM; ++lm){
    const int l = (lm==0)?0 : (lm<4)?1 : (lm<9)?2 : 3;
    atomicAdd(fr + lm*KDIM, sh[lm]*tl[l]);
  }
}

// ---------------- kernel 2: tensor product + embedding (in place) ----------------
__global__ __launch_bounds__(256) void k2_tp_embed(
    float* __restrict__ feats, const float* __restrict__ emb,
    const int* __restrict__ species, int N)
{
  int idx = blockIdx.x*256 + threadIdx.x;
  if (idx >= N*KDIM) return;
  int n = idx>>6, k = idx&63;
  float f[16], g[16];
  float* fp = feats + (size_t)n*(LMDIM*KDIM) + k;
  #pragma unroll
  for (int lm=0; lm<LMDIM; ++lm){ f[lm]=fp[lm*KDIM]; g[lm]=f[lm]; }
  all_contract(f, f, g);
  float ek = emb[species[n]*NCH + (k&15)];
  #pragma unroll
  for (int lm=0; lm<LMDIM; ++lm) fp[lm*KDIM] = g[lm]*ek;
}

// ---------------- kernel 3: second (equivariant) message pass ----------------
__global__ __launch_bounds__(256) void k3_mp(
    const float* __restrict__ pos, const float* __restrict__ Weq,
    const int* __restrict__ senders, const int* __restrict__ recv,
    const float* __restrict__ embedded, float* __restrict__ mp, int E)
{
  int e = blockIdx.x*4 + (threadIdx.x>>6);
  if (e >= E) return;
  int k = threadIdx.x & 63;
  int s = senders[e], r = recv[e];
  float sh[16], b[8];
  if (!edge_geom(pos, s, r, sh, b)) return;
  float Req[4];
  #pragma unroll
  for (int L=0;L<4;++L){
    float acc=0.0f;
    #pragma unroll
    for (int q=0;q<NB;++q) acc += b[q]*Weq[L*(NB*KDIM) + q*KDIM + k];
    Req[L]=acc;
  }
  float nb[16];
  const float* npp = embedded + (size_t)s*(LMDIM*KDIM) + k;
  #pragma unroll
  for (int lm=0; lm<LMDIM; ++lm) nb[lm]=npp[lm*KDIM];
  float out[16];
  #pragma unroll
  for (int i=0;i<16;++i) out[i]=0.0f;
  all_contract(sh, nb, out);
  float* mr = mp + (size_t)r*(LMDIM*KDIM) + k;
  #pragma unroll
  for (int lm=0; lm<LMDIM; ++lm){
    const int L = (lm==0)?0 : (lm<4)?1 : (lm<9)?2 : 3;
    atomicAdd(mr + lm*KDIM, 0.5f*out[lm]*Req[L]);   // MP_SCALING
  }
}

// ---------------- kernel 4: invariants + MLP + energy sum ----------------
template<int l>
__device__ __forceinline__ float inv_term(const float* m){
  constexpr CGT cg = real_cg(l,l,0);
  float a=0.0f;
  #pragma unroll
  for (int i=0;i<2*l+1;++i)
  #pragma unroll
  for (int j=0;j<2*l+1;++j){
    float c = cg.v[i][j][0];
    if (c != 0.0f) a += c*m[l*l+i]*m[l*l+j];
  }
  return a;
}

__global__ __launch_bounds__(64) void k4_inv_mlp(
    const float* __restrict__ mp, const float* __restrict__ W1,
    const float* __restrict__ W2, const float* __restrict__ wl,
    float* __restrict__ out, int N)
{
  __shared__ float sbuf[64];
  __shared__ float hbuf[64];
  int n = blockIdx.x;
  int k = threadIdx.x;
  const float* m0 = mp + (size_t)n*(LMDIM*KDIM) + k;
  float m[16];
  #pragma unroll
  for (int lm=0; lm<LMDIM; ++lm) m[lm]=m0[lm*KDIM];
  float inv = m[0];
  inv += inv_term<0>(m);
  inv += inv_term<1>(m);
  inv += inv_term<2>(m);
  inv += inv_term<3>(m);
  sbuf[k]=inv;
  __syncthreads();
  float a=0.0f;
  #pragma unroll
  for (int c=0;c<64;++c) a += sbuf[c]*W1[c*64+k];
  a = a / (1.0f + expf(-a));           // silu
  hbuf[k]=a;
  __syncthreads();
  float h2=0.0f;
  #pragma unroll
  for (int c=0;c<64;++c) h2 += hbuf[c]*W2[c*64+k];
  h2 = h2 / (1.0f + expf(-h2));
  float e = h2*wl[k];
  #pragma unroll
  for (int off=32; off>0; off>>=1) e += __shfl_down(e, off);
  if (k==0) atomicAdd(out, e);
}

// ---------------- launch ----------------
extern "C" void kernel_launch(void* const* d_in, const int* in_sizes, int n_in,
                              void* d_out, int out_size, void* d_ws, size_t ws_size,
                              hipStream_t stream)
{
  const float* pos     = (const float*)d_in[0];
  const float* emb     = (const float*)d_in[1];
  const float* Winv    = (const float*)d_in[2];
  const float* Weq     = (const float*)d_in[3];
  const float* W1      = (const float*)d_in[4];
  const float* W2      = (const float*)d_in[5];
  const float* wl      = (const float*)d_in[6];
  const int*   species = (const int*)d_in[7];
  const int*   senders = (const int*)d_in[8];
  const int*   recv    = (const int*)d_in[9];
  int N = in_sizes[7];
  int E = in_sizes[8];

  float* feats = (float*)d_ws;
  float* mp    = feats + (size_t)N*(LMDIM*KDIM);

  hipMemsetAsync(d_ws, 0, (size_t)N*(LMDIM*KDIM)*2*sizeof(float), stream);
  hipMemsetAsync(d_out, 0, sizeof(float), stream);

  int eb = (E+3)/4;
  k1_edge_feats<<<eb, 256, 0, stream>>>(pos, emb, Winv, species, senders, recv, feats, E);
  k2_tp_embed<<<(N*KDIM+255)/256, 256, 0, stream>>>(feats, emb, species, N);
  k3_mp<<<eb, 256, 0, stream>>>(pos, Weq, senders, recv, feats, mp, E);
  k4_inv_mlp<<<N, 64, 0, stream>>>(mp, W1, W2, wl, (float*)d_out, N);
}

// Round 2
// 518.916 us; speedup vs baseline: 1.0057x; 1.0057x over previous
//
#include <hip/hip_runtime.h>
#include <math.h>

#define L_MAX 3
#define RCUT 5.0f
#define NB 8
#define NCH 16
#define KDIM 64
#define LMDIM 16   // sum (2l+1), l=0..3

// ---------------- compile-time Clebsch-Gordan (mirrors reference _real_cg) ----------------
struct CD { double re; double im; };
struct UMat { CD m[7][7]; };
struct CGT { float v[7][7][7]; };

constexpr double cfact(int n){ double r=1.0; for(int i=2;i<=n;++i) r*=(double)i; return r; }
constexpr double cfabs(double x){ return x<0.0 ? -x : x; }
constexpr double csqrt_(double x){
  if (x<=0.0) return 0.0;
  double g = x>1.0 ? x : 1.0;
  for (int i=0;i<100;++i) g = 0.5*(g + x/g);
  return g;
}
constexpr double clebsch(int j1,int m1,int j2,int m2,int J,int M){
  if (m1+m2!=M) return 0.0;
  int ad = j1-j2; if (ad<0) ad=-ad;
  if (J<ad || J>j1+j2) return 0.0;
  double pref = csqrt_((2.0*J+1.0)*cfact(J+j1-j2)*cfact(J-j1+j2)*cfact(j1+j2-J)/cfact(j1+j2+J+1));
  pref *= csqrt_(cfact(J+M)*cfact(J-M)*cfact(j1-m1)*cfact(j1+m1)*cfact(j2-m2)*cfact(j2+m2));
  double s=0.0;
  for (int k=0;k<=j1+j2-J;++k){
    int d0=k,d1=j1+j2-J-k,d2=j1-m1-k,d3=j2+m2-k,d4=J-j2+m1+k,d5=J-j1-m2+k;
    if (d0<0||d1<0||d2<0||d3<0||d4<0||d5<0) continue;
    double den = cfact(d0)*cfact(d1)*cfact(d2)*cfact(d3)*cfact(d4)*cfact(d5);
    s += ((k&1)? -1.0:1.0)/den;
  }
  return pref*s;
}
constexpr UMat u_real(int l){
  UMat U{};
  U.m[l][l] = CD{1.0, 0.0};
  double is2 = csqrt_(0.5);
  for (int mm=1; mm<=l; ++mm){
    double sgn = (mm&1)? -1.0: 1.0;
    U.m[l+mm][l+mm] = CD{sgn*is2, 0.0};
    U.m[l+mm][l-mm] = CD{is2, 0.0};
    U.m[l-mm][l-mm] = CD{0.0, is2};
    U.m[l-mm][l+mm] = CD{0.0, -sgn*is2};
  }
  return U;
}
constexpr CGT real_cg(int l1,int l2,int L){
  double Cc[7][7][7] = {};
  for (int m1=-l1;m1<=l1;++m1)
    for (int m2=-l2;m2<=l2;++m2){
      int M=m1+m2;
      if (M>=-L && M<=L) Cc[l1+m1][l2+m2][L+M] = clebsch(l1,m1,l2,m2,L,M);
    }
  UMat U1=u_real(l1), U2=u_real(l2), U3=u_real(L);
  double Tre[7][7][7]={}, Tim[7][7][7]={};
  for (int a=0;a<2*l1+1;++a)
   for (int m=0;m<2*l1+1;++m){
     CD u1=U1.m[a][m];
     if (u1.re==0.0 && u1.im==0.0) continue;
     for (int b=0;b<2*l2+1;++b)
      for (int n=0;n<2*l2+1;++n){
        CD u2=U2.m[b][n];
        if (u2.re==0.0 && u2.im==0.0) continue;
        CD u12 = CD{u1.re*u2.re-u1.im*u2.im, u1.re*u2.im+u1.im*u2.re};
        for (int c=0;c<2*L+1;++c)
         for (int o=0;o<2*L+1;++o){
           CD u3=U3.m[c][o];
           if (u3.re==0.0 && u3.im==0.0) continue;
           double cc=Cc[m][n][o];
           if (cc==0.0) continue;
           double tr = u12.re*u3.re + u12.im*u3.im;   // u12 * conj(u3)
           double ti = u12.im*u3.re - u12.re*u3.im;
           Tre[a][b][c] += tr*cc;
           Tim[a][b][c] += ti*cc;
         }
      }
   }
  double sre=0.0, sim=0.0;
  for (int a=0;a<2*l1+1;++a) for (int b=0;b<2*l2+1;++b) for (int c=0;c<2*L+1;++c){
    sre += cfabs(Tre[a][b][c]); sim += cfabs(Tim[a][b][c]);
  }
  CGT out{};
  bool ure = (sre>=sim);
  for (int a=0;a<2*l1+1;++a) for (int b=0;b<2*l2+1;++b) for (int c=0;c<2*L+1;++c)
    out.v[a][b][c] = (float)(ure? Tre[a][b][c] : Tim[a][b][c]);
  return out;
}

// ---------------- dense factored CG for k3: Cflat[M_lm][i_lm] over j rows ----------------
// A[M][j] = sum_i Cflat[(M*16+j)][i] * sh[i], with MP_SCALING 0.5 folded in.
struct alignas(64) CFlat { float v[256][16]; };
constexpr CFlat build_cflat(){
  CFlat o{};
  for (int l1=0;l1<=3;++l1)
   for (int l2=0;l2<=3;++l2){
     int lo = l1>l2 ? l1-l2 : l2-l1;
     int hi = (l1+l2<3)? l1+l2 : 3;
     for (int L=lo; L<=hi; ++L){
       CGT cg = real_cg(l1,l2,L);
       for (int i=0;i<2*l1+1;++i)
        for (int j=0;j<2*l2+1;++j)
         for (int m=0;m<2*L+1;++m){
           o.v[(L*L+m)*16 + (l2*l2+j)][l1*l1+i] += 0.5f*cg.v[i][j][m];
         }
     }
   }
  return o;
}
__device__ const CFlat CFLAT = build_cflat();

// contraction: g[L*L+m] += C[i][j][m] * f1[l1*l1+i] * f2[l2*l2+j]
template<int l1,int l2,int L>
__device__ __forceinline__ void cg_contract(const float* __restrict__ f1,
                                            const float* __restrict__ f2,
                                            float* __restrict__ g){
  constexpr CGT cg = real_cg(l1,l2,L);
  #pragma unroll
  for (int i=0;i<2*l1+1;++i)
  #pragma unroll
  for (int j=0;j<2*l2+1;++j)
  #pragma unroll
  for (int m=0;m<2*L+1;++m){
    float c = cg.v[i][j][m];
    if (c != 0.0f) g[L*L+m] += c * f1[l1*l1+i] * f2[l2*l2+j];
  }
}

#define FOR_ALL_CG(X) \
  X(0,0,0) X(0,1,1) X(1,0,1) X(0,2,2) X(2,0,2) X(0,3,3) X(3,0,3) \
  X(1,1,0) X(1,1,1) X(1,1,2) \
  X(1,2,1) X(1,2,2) X(1,2,3) X(2,1,1) X(2,1,2) X(2,1,3) \
  X(1,3,2) X(1,3,3) X(3,1,2) X(3,1,3) \
  X(2,2,0) X(2,2,1) X(2,2,2) X(2,2,3) \
  X(2,3,1) X(2,3,2) X(2,3,3) X(3,2,1) X(3,2,2) X(3,2,3) \
  X(3,3,0) X(3,3,1) X(3,3,2) X(3,3,3)

__device__ __forceinline__ void all_contract(const float* __restrict__ f1,
                                             const float* __restrict__ f2,
                                             float* __restrict__ g){
#define XCG(a,b,c) cg_contract<a,b,c>(f1, f2, g);
  FOR_ALL_CG(XCG)
#undef XCG
}

// ---------------- geometry helpers ----------------
__device__ __forceinline__ void compute_sh(float x, float y, float z, float* sh){
  sh[0]  = 0.28209479177387814f;
  sh[1]  = 0.4886025119029199f*y;
  sh[2]  = 0.4886025119029199f*z;
  sh[3]  = 0.4886025119029199f*x;
  sh[4]  = 1.0925484305920792f*x*y;
  sh[5]  = 1.0925484305920792f*y*z;
  sh[6]  = 0.31539156525252005f*(3.0f*z*z-1.0f);
  sh[7]  = 1.0925484305920792f*x*z;
  sh[8]  = 0.5462742152960396f*(x*x-y*y);
  sh[9]  = 0.5900435899266435f*y*(3.0f*x*x-y*y);
  sh[10] = 2.890611442640554f*x*y*z;
  sh[11] = 0.4570457994644658f*y*(5.0f*z*z-1.0f);
  sh[12] = 0.3731763325901154f*z*(5.0f*z*z-3.0f);
  sh[13] = 0.4570457994644658f*x*(5.0f*z*z-1.0f);
  sh[14] = 1.445305721320277f*z*(x*x-y*y);
  sh[15] = 0.5900435899266435f*x*(x*x-3.0f*y*y);
}

// returns true if edge active (d < RC); fills sh[16], b[8]
__device__ __forceinline__ bool edge_geom(const float* __restrict__ pos, int s, int r,
                                          float* sh, float* b){
  float dx = pos[r*3+0]-pos[s*3+0];
  float dy = pos[r*3+1]-pos[s*3+1];
  float dz = pos[r*3+2]-pos[s*3+2];
  float d  = sqrtf(dx*dx+dy*dy+dz*dz + 1e-12f);
  if (d >= RCUT) return false;
  float inv_d = 1.0f/d;
  compute_sh(dx*inv_d, dy*inv_d, dz*inv_d, sh);
  float fc = 0.5f*(cosf(d*(3.14159265358979323846f/RCUT))+1.0f);
  #pragma unroll
  for (int q=0;q<NB;++q){
    float t = (d - (float)((double)q*(5.0/7.0))) * 1.6f;  // /sigma, sigma=0.625
    b[q] = expf(-0.5f*t*t)*fc;
  }
  return true;
}

// ---------------- kernel 1: edges -> feats (first message pass) ----------------
__global__ __launch_bounds__(256) void k1_edge_feats(
    const float* __restrict__ pos, const float* __restrict__ emb,
    const float* __restrict__ Winv, const int* __restrict__ species,
    const int* __restrict__ senders, const int* __restrict__ recv,
    float* __restrict__ feats, int E)
{
  int e = blockIdx.x*4 + (threadIdx.x>>6);
  if (e >= E) return;
  int lane = threadIdx.x & 63;
  int s = senders[e], r = recv[e];
  float sh[16], b[8];
  if (!edge_geom(pos, s, r, sh, b)) return;
  // R[l][n] = sum_q b[q] * Winv[l][q][n]
  float R[4][4];
  #pragma unroll
  for (int l=0;l<4;++l)
    #pragma unroll
    for (int n=0;n<4;++n){
      float acc=0.0f;
      #pragma unroll
      for (int q=0;q<NB;++q) acc += b[q]*Winv[l*32+q*4+n];
      R[l][n]=acc;
    }
  int n = lane>>4, c = lane&15;
  float xc = emb[species[s]*NCH + c];
  float tl[4];
  #pragma unroll
  for (int l=0;l<4;++l) tl[l] = 0.5f * xc * R[l][n];   // MP_SCALING
  float* fr = feats + (size_t)r*(LMDIM*KDIM) + lane;
  #pragma unroll
  for (int lm=0; lm<LMDIM; ++lm){
    const int l = (lm==0)?0 : (lm<4)?1 : (lm<9)?2 : 3;
    atomicAdd(fr + lm*KDIM, sh[lm]*tl[l]);
  }
}

// ---------------- kernel 2: tensor product + embedding (in place) ----------------
__global__ __launch_bounds__(256) void k2_tp_embed(
    float* __restrict__ feats, const float* __restrict__ emb,
    const int* __restrict__ species, int N)
{
  int idx = blockIdx.x*256 + threadIdx.x;
  if (idx >= N*KDIM) return;
  int n = idx>>6, k = idx&63;
  float f[16], g[16];
  float* fp = feats + (size_t)n*(LMDIM*KDIM) + k;
  #pragma unroll
  for (int lm=0; lm<LMDIM; ++lm){ f[lm]=fp[lm*KDIM]; g[lm]=f[lm]; }
  all_contract(f, f, g);
  float ek = emb[species[n]*NCH + (k&15)];
  #pragma unroll
  for (int lm=0; lm<LMDIM; ++lm) fp[lm*KDIM] = g[lm]*ek;
}

// ---------------- kernel 3: second (equivariant) message pass, factored ----------------
// out[M][k] = Req[L(M)][k] * sum_j A[M][j] * nb[j][k],  A built cooperatively per wave.
__global__ __launch_bounds__(256) void k3_mp(
    const float* __restrict__ pos, const float* __restrict__ Weq,
    const int* __restrict__ senders, const int* __restrict__ recv,
    const float* __restrict__ embedded, float* __restrict__ mp, int E)
{
  __shared__ __align__(16) float Ash[4][256];
  int wv = threadIdx.x>>6;
  int e = blockIdx.x*4 + wv;
  if (e >= E) return;
  int k = threadIdx.x & 63;
  int s = senders[e], r = recv[e];
  float sh[16], b[8];
  if (!edge_geom(pos, s, r, sh, b)) return;   // wave-uniform exit
  float Req[4];
  #pragma unroll
  for (int L=0;L<4;++L){
    float acc=0.0f;
    #pragma unroll
    for (int q=0;q<NB;++q) acc += b[q]*Weq[L*(NB*KDIM) + q*KDIM + k];
    Req[L]=acc;
  }
  float nb[16];
  const float* npp = embedded + (size_t)s*(LMDIM*KDIM) + k;
  #pragma unroll
  for (int lm=0; lm<LMDIM; ++lm) nb[lm]=npp[lm*KDIM];

  // cooperative A build: lane k computes entries k, 64+k, 128+k, 192+k
  float* Arow = Ash[wv];
  #pragma unroll
  for (int q=0;q<4;++q){
    int ent = q*64 + k;
    const float4* c4 = (const float4*)CFLAT.v[ent];
    float4 c0=c4[0], c1=c4[1], c2=c4[2], c3=c4[3];
    float acc = c0.x*sh[0]+c0.y*sh[1]+c0.z*sh[2]+c0.w*sh[3]
              + c1.x*sh[4]+c1.y*sh[5]+c1.z*sh[6]+c1.w*sh[7]
              + c2.x*sh[8]+c2.y*sh[9]+c2.z*sh[10]+c2.w*sh[11]
              + c3.x*sh[12]+c3.y*sh[13]+c3.z*sh[14]+c3.w*sh[15];
    Arow[ent] = acc;
  }
  // same-wave LDS RAW: compiler inserts lgkmcnt wait; no cross-wave dependency (per-wave region)
  float* mr = mp + (size_t)r*(LMDIM*KDIM) + k;
  #pragma unroll
  for (int M=0;M<16;++M){
    const int L = (M==0)?0 : (M<4)?1 : (M<9)?2 : 3;
    const float4* a4 = (const float4*)(Arow + M*16);
    float4 a0=a4[0], a1=a4[1], a2=a4[2], a3=a4[3];
    float acc = a0.x*nb[0]+a0.y*nb[1]+a0.z*nb[2]+a0.w*nb[3]
              + a1.x*nb[4]+a1.y*nb[5]+a1.z*nb[6]+a1.w*nb[7]
              + a2.x*nb[8]+a2.y*nb[9]+a2.z*nb[10]+a2.w*nb[11]
              + a3.x*nb[12]+a3.y*nb[13]+a3.z*nb[14]+a3.w*nb[15];
    atomicAdd(mr + M*KDIM, acc*Req[L]);
  }
}

// ---------------- kernel 4: invariants + MLP + energy sum ----------------
template<int l>
__device__ __forceinline__ float inv_term(const float* m){
  constexpr CGT cg = real_cg(l,l,0);
  float a=0.0f;
  #pragma unroll
  for (int i=0;i<2*l+1;++i)
  #pragma unroll
  for (int j=0;j<2*l+1;++j){
    float c = cg.v[i][j][0];
    if (c != 0.0f) a += c*m[l*l+i]*m[l*l+j];
  }
  return a;
}

__global__ __launch_bounds__(64) void k4_inv_mlp(
    const float* __restrict__ mp, const float* __restrict__ W1,
    const float* __restrict__ W2, const float* __restrict__ wl,
    float* __restrict__ out, int N)
{
  __shared__ float sbuf[64];
  __shared__ float hbuf[64];
  int n = blockIdx.x;
  int k = threadIdx.x;
  const float* m0 = mp + (size_t)n*(LMDIM*KDIM) + k;
  float m[16];
  #pragma unroll
  for (int lm=0; lm<LMDIM; ++lm) m[lm]=m0[lm*KDIM];
  float inv = m[0];
  inv += inv_term<0>(m);
  inv += inv_term<1>(m);
  inv += inv_term<2>(m);
  inv += inv_term<3>(m);
  sbuf[k]=inv;
  __syncthreads();
  float a=0.0f;
  #pragma unroll
  for (int c=0;c<64;++c) a += sbuf[c]*W1[c*64+k];
  a = a / (1.0f + expf(-a));           // silu
  hbuf[k]=a;
  __syncthreads();
  float h2=0.0f;
  #pragma unroll
  for (int c=0;c<64;++c) h2 += hbuf[c]*W2[c*64+k];
  h2 = h2 / (1.0f + expf(-h2));
  float e = h2*wl[k];
  #pragma unroll
  for (int off=32; off>0; off>>=1) e += __shfl_down(e, off);
  if (k==0) atomicAdd(out, e);
}

// ---------------- launch ----------------
extern "C" void kernel_launch(void* const* d_in, const int* in_sizes, int n_in,
                              void* d_out, int out_size, void* d_ws, size_t ws_size,
                              hipStream_t stream)
{
  const float* pos     = (const float*)d_in[0];
  const float* emb     = (const float*)d_in[1];
  const float* Winv    = (const float*)d_in[2];
  const float* Weq     = (const float*)d_in[3];
  const float* W1      = (const float*)d_in[4];
  const float* W2      = (const float*)d_in[5];
  const float* wl      = (const float*)d_in[6];
  const int*   species = (const int*)d_in[7];
  const int*   senders = (const int*)d_in[8];
  const int*   recv    = (const int*)d_in[9];
  int N = in_sizes[7];
  int E = in_sizes[8];

  float* feats = (float*)d_ws;
  float* mp    = feats + (size_t)N*(LMDIM*KDIM);

  hipMemsetAsync(d_ws, 0, (size_t)N*(LMDIM*KDIM)*2*sizeof(float), stream);
  hipMemsetAsync(d_out, 0, sizeof(float), stream);

  int eb = (E+3)/4;
  k1_edge_feats<<<eb, 256, 0, stream>>>(pos, emb, Winv, species, senders, recv, feats, E);
  k2_tp_embed<<<(N*KDIM+255)/256, 256, 0, stream>>>(feats, emb, species, N);
  k3_mp<<<eb, 256, 0, stream>>>(pos, Weq, senders, recv, feats, mp, E);
  k4_inv_mlp<<<N, 64, 0, stream>>>(mp, W1, W2, wl, (float*)d_out, N);
}

// Round 3
// 400.003 us; speedup vs baseline: 1.3047x; 1.2973x over previous
//
#include <hip/hip_runtime.h>
#include <math.h>

#define L_MAX 3
#define RCUT 5.0f
#define NB 8
#define NCH 16
#define KDIM 64
#define LMDIM 16   // sum (2l+1), l=0..3

// ---------------- compile-time Clebsch-Gordan (mirrors reference _real_cg) ----------------
struct CD { double re; double im; };
struct UMat { CD m[7][7]; };
struct CGT { float v[7][7][7]; };

constexpr double cfact(int n){ double r=1.0; for(int i=2;i<=n;++i) r*=(double)i; return r; }
constexpr double cfabs(double x){ return x<0.0 ? -x : x; }
constexpr double csqrt_(double x){
  if (x<=0.0) return 0.0;
  double g = x>1.0 ? x : 1.0;
  for (int i=0;i<100;++i) g = 0.5*(g + x/g);
  return g;
}
constexpr double clebsch(int j1,int m1,int j2,int m2,int J,int M){
  if (m1+m2!=M) return 0.0;
  int ad = j1-j2; if (ad<0) ad=-ad;
  if (J<ad || J>j1+j2) return 0.0;
  double pref = csqrt_((2.0*J+1.0)*cfact(J+j1-j2)*cfact(J-j1+j2)*cfact(j1+j2-J)/cfact(j1+j2+J+1));
  pref *= csqrt_(cfact(J+M)*cfact(J-M)*cfact(j1-m1)*cfact(j1+m1)*cfact(j2-m2)*cfact(j2+m2));
  double s=0.0;
  for (int k=0;k<=j1+j2-J;++k){
    int d0=k,d1=j1+j2-J-k,d2=j1-m1-k,d3=j2+m2-k,d4=J-j2+m1+k,d5=J-j1-m2+k;
    if (d0<0||d1<0||d2<0||d3<0||d4<0||d5<0) continue;
    double den = cfact(d0)*cfact(d1)*cfact(d2)*cfact(d3)*cfact(d4)*cfact(d5);
    s += ((k&1)? -1.0:1.0)/den;
  }
  return pref*s;
}
constexpr UMat u_real(int l){
  UMat U{};
  U.m[l][l] = CD{1.0, 0.0};
  double is2 = csqrt_(0.5);
  for (int mm=1; mm<=l; ++mm){
    double sgn = (mm&1)? -1.0: 1.0;
    U.m[l+mm][l+mm] = CD{sgn*is2, 0.0};
    U.m[l+mm][l-mm] = CD{is2, 0.0};
    U.m[l-mm][l-mm] = CD{0.0, is2};
    U.m[l-mm][l+mm] = CD{0.0, -sgn*is2};
  }
  return U;
}
constexpr CGT real_cg(int l1,int l2,int L){
  double Cc[7][7][7] = {};
  for (int m1=-l1;m1<=l1;++m1)
    for (int m2=-l2;m2<=l2;++m2){
      int M=m1+m2;
      if (M>=-L && M<=L) Cc[l1+m1][l2+m2][L+M] = clebsch(l1,m1,l2,m2,L,M);
    }
  UMat U1=u_real(l1), U2=u_real(l2), U3=u_real(L);
  double Tre[7][7][7]={}, Tim[7][7][7]={};
  for (int a=0;a<2*l1+1;++a)
   for (int m=0;m<2*l1+1;++m){
     CD u1=U1.m[a][m];
     if (u1.re==0.0 && u1.im==0.0) continue;
     for (int b=0;b<2*l2+1;++b)
      for (int n=0;n<2*l2+1;++n){
        CD u2=U2.m[b][n];
        if (u2.re==0.0 && u2.im==0.0) continue;
        CD u12 = CD{u1.re*u2.re-u1.im*u2.im, u1.re*u2.im+u1.im*u2.re};
        for (int c=0;c<2*L+1;++c)
         for (int o=0;o<2*L+1;++o){
           CD u3=U3.m[c][o];
           if (u3.re==0.0 && u3.im==0.0) continue;
           double cc=Cc[m][n][o];
           if (cc==0.0) continue;
           double tr = u12.re*u3.re + u12.im*u3.im;   // u12 * conj(u3)
           double ti = u12.im*u3.re - u12.re*u3.im;
           Tre[a][b][c] += tr*cc;
           Tim[a][b][c] += ti*cc;
         }
      }
   }
  double sre=0.0, sim=0.0;
  for (int a=0;a<2*l1+1;++a) for (int b=0;b<2*l2+1;++b) for (int c=0;c<2*L+1;++c){
    sre += cfabs(Tre[a][b][c]); sim += cfabs(Tim[a][b][c]);
  }
  CGT out{};
  bool ure = (sre>=sim);
  for (int a=0;a<2*l1+1;++a) for (int b=0;b<2*l2+1;++b) for (int c=0;c<2*L+1;++c)
    out.v[a][b][c] = (float)(ure? Tre[a][b][c] : Tim[a][b][c]);
  return out;
}

// ---------------- dense factored CG for pass 2: A[M][j] = sum_i Cflat[M*16+j][i]*sh[i]
// MP_SCALING 0.5 folded in.
struct alignas(64) CFlat { float v[256][16]; };
constexpr CFlat build_cflat(){
  CFlat o{};
  for (int l1=0;l1<=3;++l1)
   for (int l2=0;l2<=3;++l2){
     int lo = l1>l2 ? l1-l2 : l2-l1;
     int hi = (l1+l2<3)? l1+l2 : 3;
     for (int L=lo; L<=hi; ++L){
       CGT cg = real_cg(l1,l2,L);
       for (int i=0;i<2*l1+1;++i)
        for (int j=0;j<2*l2+1;++j)
         for (int m=0;m<2*L+1;++m){
           o.v[(L*L+m)*16 + (l2*l2+j)][l1*l1+i] += 0.5f*cg.v[i][j][m];
         }
     }
   }
  return o;
}
__device__ const CFlat CFLAT = build_cflat();

template<int l1,int l2,int L>
__device__ __forceinline__ void cg_contract(const float* __restrict__ f1,
                                            const float* __restrict__ f2,
                                            float* __restrict__ g){
  constexpr CGT cg = real_cg(l1,l2,L);
  #pragma unroll
  for (int i=0;i<2*l1+1;++i)
  #pragma unroll
  for (int j=0;j<2*l2+1;++j)
  #pragma unroll
  for (int m=0;m<2*L+1;++m){
    float c = cg.v[i][j][m];
    if (c != 0.0f) g[L*L+m] += c * f1[l1*l1+i] * f2[l2*l2+j];
  }
}

#define FOR_ALL_CG(X) \
  X(0,0,0) X(0,1,1) X(1,0,1) X(0,2,2) X(2,0,2) X(0,3,3) X(3,0,3) \
  X(1,1,0) X(1,1,1) X(1,1,2) \
  X(1,2,1) X(1,2,2) X(1,2,3) X(2,1,1) X(2,1,2) X(2,1,3) \
  X(1,3,2) X(1,3,3) X(3,1,2) X(3,1,3) \
  X(2,2,0) X(2,2,1) X(2,2,2) X(2,2,3) \
  X(2,3,1) X(2,3,2) X(2,3,3) X(3,2,1) X(3,2,2) X(3,2,3) \
  X(3,3,0) X(3,3,1) X(3,3,2) X(3,3,3)

__device__ __forceinline__ void all_contract(const float* __restrict__ f1,
                                             const float* __restrict__ f2,
                                             float* __restrict__ g){
#define XCG(a,b,c) cg_contract<a,b,c>(f1, f2, g);
  FOR_ALL_CG(XCG)
#undef XCG
}

// ---------------- geometry ----------------
__device__ __forceinline__ void compute_sh(float x, float y, float z, float* sh){
  sh[0]  = 0.28209479177387814f;
  sh[1]  = 0.4886025119029199f*y;
  sh[2]  = 0.4886025119029199f*z;
  sh[3]  = 0.4886025119029199f*x;
  sh[4]  = 1.0925484305920792f*x*y;
  sh[5]  = 1.0925484305920792f*y*z;
  sh[6]  = 0.31539156525252005f*(3.0f*z*z-1.0f);
  sh[7]  = 1.0925484305920792f*x*z;
  sh[8]  = 0.5462742152960396f*(x*x-y*y);
  sh[9]  = 0.5900435899266435f*y*(3.0f*x*x-y*y);
  sh[10] = 2.890611442640554f*x*y*z;
  sh[11] = 0.4570457994644658f*y*(5.0f*z*z-1.0f);
  sh[12] = 0.3731763325901154f*z*(5.0f*z*z-3.0f);
  sh[13] = 0.4570457994644658f*x*(5.0f*z*z-1.0f);
  sh[14] = 1.445305721320277f*z*(x*x-y*y);
  sh[15] = 0.5900435899266435f*x*(x*x-3.0f*y*y);
}

// d from (dx,dy,dz); fills sh[16], b[8]; returns false if d>=RC
__device__ __forceinline__ bool geom_from_d(float dx, float dy, float dz,
                                            float* sh, float* b){
  float d = sqrtf(dx*dx+dy*dy+dz*dz + 1e-12f);
  if (d >= RCUT) return false;
  float inv_d = 1.0f/d;
  compute_sh(dx*inv_d, dy*inv_d, dz*inv_d, sh);
  float fc = 0.5f*(cosf(d*(3.14159265358979323846f/RCUT))+1.0f);
  #pragma unroll
  for (int q=0;q<NB;++q){
    float t = (d - (float)((double)q*(5.0/7.0))) * 1.6f;  // sigma=0.625
    b[q] = expf(-0.5f*t*t)*fc;
  }
  return true;
}

// ---------------- CSR build ----------------
__global__ __launch_bounds__(256) void k_hist(const int* __restrict__ recv,
                                              int* __restrict__ counts, int E){
  int e = blockIdx.x*256 + threadIdx.x;
  if (e < E) atomicAdd(&counts[recv[e]], 1);
}

__global__ __launch_bounds__(256) void k_scan(const int* __restrict__ counts,
                                              int* __restrict__ offsets, int N){
  __shared__ int buf[256];
  __shared__ int carry_s;
  if (threadIdx.x==0) carry_s = 0;
  __syncthreads();
  for (int base=0; base<N; base+=256){
    int i = base + threadIdx.x;
    int v = (i<N)? counts[i] : 0;
    buf[threadIdx.x] = v;
    __syncthreads();
    int acc = v;
    #pragma unroll
    for (int off=1; off<256; off<<=1){
      int t = (threadIdx.x >= off)? buf[threadIdx.x-off] : 0;
      __syncthreads();
      acc += t;
      buf[threadIdx.x] = acc;
      __syncthreads();
    }
    if (i<N) offsets[i] = carry_s + acc - v;   // exclusive
    int total = buf[255];
    __syncthreads();
    if (threadIdx.x==0) carry_s += total;
    __syncthreads();
  }
}

__global__ __launch_bounds__(256) void k_scatter(const int* __restrict__ senders,
                                                 const int* __restrict__ recv,
                                                 const int* __restrict__ offsets,
                                                 int* __restrict__ cursor,
                                                 int* __restrict__ bucket, int E){
  int e = blockIdx.x*256 + threadIdx.x;
  if (e >= E) return;
  int r = recv[e];
  int p = atomicAdd(&cursor[r], 1);
  bucket[offsets[r] + p] = senders[e];
}

// ---------------- kernel A: gather pass-1 + tensor product + embed ----------------
__global__ __launch_bounds__(256) void kA_gather_tp(
    const float* __restrict__ pos, const float* __restrict__ emb,
    const float* __restrict__ Winv, const int* __restrict__ species,
    const int* __restrict__ offsets, const int* __restrict__ counts,
    const int* __restrict__ bucket, float* __restrict__ feats, int N)
{
  int wv = threadIdx.x>>6;
  int r = blockIdx.x*4 + wv;
  if (r >= N) return;
  int lane = threadIdx.x & 63;
  int n = lane>>4, c = lane&15;
  float prx = pos[r*3+0], pry = pos[r*3+1], prz = pos[r*3+2];
  int off = offsets[r], cnt = counts[r];
  float f[16];
  #pragma unroll
  for (int lm=0; lm<16; ++lm) f[lm]=0.0f;
  for (int j=0; j<cnt; ++j){
    int s = bucket[off+j];
    float dx = prx - pos[s*3+0];
    float dy = pry - pos[s*3+1];
    float dz = prz - pos[s*3+2];
    float sh[16], b[8];
    if (!geom_from_d(dx,dy,dz,sh,b)) continue;   // wave-uniform
    float tl[4];
    #pragma unroll
    for (int l=0;l<4;++l){
      float acc=0.0f;
      #pragma unroll
      for (int q=0;q<NB;++q) acc += b[q]*Winv[l*32+q*4+n];
      tl[l]=acc;
    }
    float xc = 0.5f * emb[species[s]*NCH + c];   // MP_SCALING
    #pragma unroll
    for (int l=0;l<4;++l) tl[l] *= xc;
    #pragma unroll
    for (int lm=0; lm<16; ++lm){
      const int l = (lm==0)?0 : (lm<4)?1 : (lm<9)?2 : 3;
      f[lm] += sh[lm]*tl[l];
    }
  }
  // tensor product + self-embedding
  float g[16];
  #pragma unroll
  for (int lm=0; lm<16; ++lm) g[lm]=f[lm];
  all_contract(f, f, g);
  float ek = emb[species[r]*NCH + c];
  float* fp = feats + (size_t)r*(LMDIM*KDIM) + lane;
  #pragma unroll
  for (int lm=0; lm<16; ++lm) fp[lm*KDIM] = g[lm]*ek;
}

// ---------------- kernel B: gather pass-2 + invariants + MLP ----------------
template<int l>
__device__ __forceinline__ float inv_term(const float* m){
  constexpr CGT cg = real_cg(l,l,0);
  float a=0.0f;
  #pragma unroll
  for (int i=0;i<2*l+1;++i)
  #pragma unroll
  for (int j=0;j<2*l+1;++j){
    float c = cg.v[i][j][0];
    if (c != 0.0f) a += c*m[l*l+i]*m[l*l+j];
  }
  return a;
}

__global__ __launch_bounds__(256) void kB_mp2_mlp(
    const float* __restrict__ pos, const float* __restrict__ Weq,
    const float* __restrict__ W1, const float* __restrict__ W2,
    const float* __restrict__ wl,
    const int* __restrict__ offsets, const int* __restrict__ counts,
    const int* __restrict__ bucket, const float* __restrict__ embedded,
    float* __restrict__ eatom, int N)
{
  __shared__ __align__(16) float Ash[4][256];
  int wv = threadIdx.x>>6;
  int r = blockIdx.x*4 + wv;
  if (r >= N) return;
  int k = threadIdx.x & 63;
  float prx = pos[r*3+0], pry = pos[r*3+1], prz = pos[r*3+2];
  int off = offsets[r], cnt = counts[r];
  float* Arow = Ash[wv];
  float m[16];
  #pragma unroll
  for (int i=0;i<16;++i) m[i]=0.0f;

  for (int j=0; j<cnt; ++j){
    int s = bucket[off+j];
    float dx = prx - pos[s*3+0];
    float dy = pry - pos[s*3+1];
    float dz = prz - pos[s*3+2];
    float sh[16], b[8];
    if (!geom_from_d(dx,dy,dz,sh,b)) continue;   // wave-uniform
    float Req[4];
    #pragma unroll
    for (int L=0;L<4;++L){
      float acc=0.0f;
      #pragma unroll
      for (int q=0;q<NB;++q) acc += b[q]*Weq[L*(NB*KDIM) + q*KDIM + k];
      Req[L]=acc;
    }
    float nb[16];
    const float* npp = embedded + (size_t)s*(LMDIM*KDIM) + k;
    #pragma unroll
    for (int lm=0; lm<16; ++lm) nb[lm]=npp[lm*KDIM];
    // cooperative A build: lane k computes entries k,64+k,128+k,192+k
    #pragma unroll
    for (int q=0;q<4;++q){
      int ent = q*64 + k;
      const float4* c4 = (const float4*)CFLAT.v[ent];
      float4 c0=c4[0], c1=c4[1], c2=c4[2], c3=c4[3];
      float acc = c0.x*sh[0]+c0.y*sh[1]+c0.z*sh[2]+c0.w*sh[3]
                + c1.x*sh[4]+c1.y*sh[5]+c1.z*sh[6]+c1.w*sh[7]
                + c2.x*sh[8]+c2.y*sh[9]+c2.z*sh[10]+c2.w*sh[11]
                + c3.x*sh[12]+c3.y*sh[13]+c3.z*sh[14]+c3.w*sh[15];
      Arow[ent] = acc;
    }
    // same-wave LDS RAW -> compiler lgkmcnt
    #pragma unroll
    for (int M=0;M<16;++M){
      const int L = (M==0)?0 : (M<4)?1 : (M<9)?2 : 3;
      const float4* a4 = (const float4*)(Arow + M*16);
      float4 a0=a4[0], a1=a4[1], a2=a4[2], a3=a4[3];
      float acc = a0.x*nb[0]+a0.y*nb[1]+a0.z*nb[2]+a0.w*nb[3]
                + a1.x*nb[4]+a1.y*nb[5]+a1.z*nb[6]+a1.w*nb[7]
                + a2.x*nb[8]+a2.y*nb[9]+a2.z*nb[10]+a2.w*nb[11]
                + a3.x*nb[12]+a3.y*nb[13]+a3.z*nb[14]+a3.w*nb[15];
      m[M] += acc*Req[L];
    }
  }

  // invariants (0.5 MP_SCALING already folded into CFLAT -> m)
  float inv = m[0];
  inv += inv_term<0>(m);
  inv += inv_term<1>(m);
  inv += inv_term<2>(m);
  inv += inv_term<3>(m);
  // per-wave MLP via LDS broadcast (reuse Arow)
  Arow[k] = inv;
  float a=0.0f;
  #pragma unroll
  for (int c=0;c<64;++c) a += Arow[c]*W1[c*64+k];
  a = a / (1.0f + expf(-a));           // silu
  Arow[64+k] = a;
  float h2=0.0f;
  #pragma unroll
  for (int c=0;c<64;++c) h2 += Arow[64+c]*W2[c*64+k];
  h2 = h2 / (1.0f + expf(-h2));
  float e = h2*wl[k];
  #pragma unroll
  for (int o=32; o>0; o>>=1) e += __shfl_down(e, o);
  if (k==0) eatom[r] = e;
}

__global__ __launch_bounds__(256) void k_reduce(const float* __restrict__ eatom,
                                                float* __restrict__ out, int N){
  __shared__ float buf[256];
  float a=0.0f;
  for (int i=threadIdx.x; i<N; i+=256) a += eatom[i];
  buf[threadIdx.x]=a;
  __syncthreads();
  #pragma unroll
  for (int o=128;o>0;o>>=1){
    if (threadIdx.x<o) buf[threadIdx.x]+=buf[threadIdx.x+o];
    __syncthreads();
  }
  if (threadIdx.x==0) out[0]=buf[0];
}

// ---------------- launch ----------------
extern "C" void kernel_launch(void* const* d_in, const int* in_sizes, int n_in,
                              void* d_out, int out_size, void* d_ws, size_t ws_size,
                              hipStream_t stream)
{
  const float* pos     = (const float*)d_in[0];
  const float* emb     = (const float*)d_in[1];
  const float* Winv    = (const float*)d_in[2];
  const float* Weq     = (const float*)d_in[3];
  const float* W1      = (const float*)d_in[4];
  const float* W2      = (const float*)d_in[5];
  const float* wl      = (const float*)d_in[6];
  const int*   species = (const int*)d_in[7];
  const int*   senders = (const int*)d_in[8];
  const int*   recv    = (const int*)d_in[9];
  int N = in_sizes[7];
  int E = in_sizes[8];

  char* ws = (char*)d_ws;
  float* feats   = (float*)ws;                         // N*1024 f32
  char*  p       = ws + (size_t)N*(LMDIM*KDIM)*sizeof(float);
  int*   counts  = (int*)p;                            // N
  int*   cursor  = counts + N;                         // N
  int*   offsets = cursor + N;                         // N
  int*   bucket  = offsets + N;                        // E
  float* eatom   = (float*)(bucket + E);               // N

  hipMemsetAsync(counts, 0, 2*(size_t)N*sizeof(int), stream);  // counts+cursor

  int ebl = (E+255)/256;
  int abl = (N+3)/4;
  k_hist<<<ebl, 256, 0, stream>>>(recv, counts, E);
  k_scan<<<1, 256, 0, stream>>>(counts, offsets, N);
  k_scatter<<<ebl, 256, 0, stream>>>(senders, recv, offsets, cursor, bucket, E);
  kA_gather_tp<<<abl, 256, 0, stream>>>(pos, emb, Winv, species, offsets, counts, bucket, feats, N);
  kB_mp2_mlp<<<abl, 256, 0, stream>>>(pos, Weq, W1, W2, wl, offsets, counts, bucket, feats, eatom, N);
  k_reduce<<<1, 256, 0, stream>>>(eatom, (float*)d_out, N);
}

// Round 4
// 245.615 us; speedup vs baseline: 2.1248x; 1.6286x over previous
//
#include <hip/hip_runtime.h>
#include <math.h>

#define L_MAX 3
#define RCUT 5.0f
#define NB 8
#define NCH 16
#define KDIM 64
#define LMDIM 16   // sum (2l+1), l=0..3
#define GSTRIDE 40 // per-edge geometry floats: sh[16], b[8], R[16]

// ---------------- compile-time Clebsch-Gordan (mirrors reference _real_cg) ----------------
struct CD { double re; double im; };
struct UMat { CD m[7][7]; };
struct CGT { float v[7][7][7]; };

constexpr double cfact(int n){ double r=1.0; for(int i=2;i<=n;++i) r*=(double)i; return r; }
constexpr double cfabs(double x){ return x<0.0 ? -x : x; }
constexpr double csqrt_(double x){
  if (x<=0.0) return 0.0;
  double g = x>1.0 ? x : 1.0;
  for (int i=0;i<100;++i) g = 0.5*(g + x/g);
  return g;
}
constexpr double clebsch(int j1,int m1,int j2,int m2,int J,int M){
  if (m1+m2!=M) return 0.0;
  int ad = j1-j2; if (ad<0) ad=-ad;
  if (J<ad || J>j1+j2) return 0.0;
  double pref = csqrt_((2.0*J+1.0)*cfact(J+j1-j2)*cfact(J-j1+j2)*cfact(j1+j2-J)/cfact(j1+j2+J+1));
  pref *= csqrt_(cfact(J+M)*cfact(J-M)*cfact(j1-m1)*cfact(j1+m1)*cfact(j2-m2)*cfact(j2+m2));
  double s=0.0;
  for (int k=0;k<=j1+j2-J;++k){
    int d0=k,d1=j1+j2-J-k,d2=j1-m1-k,d3=j2+m2-k,d4=J-j2+m1+k,d5=J-j1-m2+k;
    if (d0<0||d1<0||d2<0||d3<0||d4<0||d5<0) continue;
    double den = cfact(d0)*cfact(d1)*cfact(d2)*cfact(d3)*cfact(d4)*cfact(d5);
    s += ((k&1)? -1.0:1.0)/den;
  }
  return pref*s;
}
constexpr UMat u_real(int l){
  UMat U{};
  U.m[l][l] = CD{1.0, 0.0};
  double is2 = csqrt_(0.5);
  for (int mm=1; mm<=l; ++mm){
    double sgn = (mm&1)? -1.0: 1.0;
    U.m[l+mm][l+mm] = CD{sgn*is2, 0.0};
    U.m[l+mm][l-mm] = CD{is2, 0.0};
    U.m[l-mm][l-mm] = CD{0.0, is2};
    U.m[l-mm][l+mm] = CD{0.0, -sgn*is2};
  }
  return U;
}
constexpr CGT real_cg(int l1,int l2,int L){
  double Cc[7][7][7] = {};
  for (int m1=-l1;m1<=l1;++m1)
    for (int m2=-l2;m2<=l2;++m2){
      int M=m1+m2;
      if (M>=-L && M<=L) Cc[l1+m1][l2+m2][L+M] = clebsch(l1,m1,l2,m2,L,M);
    }
  UMat U1=u_real(l1), U2=u_real(l2), U3=u_real(L);
  double Tre[7][7][7]={}, Tim[7][7][7]={};
  for (int a=0;a<2*l1+1;++a)
   for (int m=0;m<2*l1+1;++m){
     CD u1=U1.m[a][m];
     if (u1.re==0.0 && u1.im==0.0) continue;
     for (int b=0;b<2*l2+1;++b)
      for (int n=0;n<2*l2+1;++n){
        CD u2=U2.m[b][n];
        if (u2.re==0.0 && u2.im==0.0) continue;
        CD u12 = CD{u1.re*u2.re-u1.im*u2.im, u1.re*u2.im+u1.im*u2.re};
        for (int c=0;c<2*L+1;++c)
         for (int o=0;o<2*L+1;++o){
           CD u3=U3.m[c][o];
           if (u3.re==0.0 && u3.im==0.0) continue;
           double cc=Cc[m][n][o];
           if (cc==0.0) continue;
           double tr = u12.re*u3.re + u12.im*u3.im;   // u12 * conj(u3)
           double ti = u12.im*u3.re - u12.re*u3.im;
           Tre[a][b][c] += tr*cc;
           Tim[a][b][c] += ti*cc;
         }
      }
   }
  double sre=0.0, sim=0.0;
  for (int a=0;a<2*l1+1;++a) for (int b=0;b<2*l2+1;++b) for (int c=0;c<2*L+1;++c){
    sre += cfabs(Tre[a][b][c]); sim += cfabs(Tim[a][b][c]);
  }
  CGT out{};
  bool ure = (sre>=sim);
  for (int a=0;a<2*l1+1;++a) for (int b=0;b<2*l2+1;++b) for (int c=0;c<2*L+1;++c)
    out.v[a][b][c] = (float)(ure? Tre[a][b][c] : Tim[a][b][c]);
  return out;
}

// A[M][j] = sum_i Cflat[M*16+j][i]*sh[i], MP_SCALING 0.5 folded in.
struct alignas(64) CFlat { float v[256][16]; };
constexpr CFlat build_cflat(){
  CFlat o{};
  for (int l1=0;l1<=3;++l1)
   for (int l2=0;l2<=3;++l2){
     int lo = l1>l2 ? l1-l2 : l2-l1;
     int hi = (l1+l2<3)? l1+l2 : 3;
     for (int L=lo; L<=hi; ++L){
       CGT cg = real_cg(l1,l2,L);
       for (int i=0;i<2*l1+1;++i)
        for (int j=0;j<2*l2+1;++j)
         for (int m=0;m<2*L+1;++m){
           o.v[(L*L+m)*16 + (l2*l2+j)][l1*l1+i] += 0.5f*cg.v[i][j][m];
         }
     }
   }
  return o;
}
__device__ const CFlat CFLAT = build_cflat();

template<int l1,int l2,int L>
__device__ __forceinline__ void cg_contract(const float* __restrict__ f1,
                                            const float* __restrict__ f2,
                                            float* __restrict__ g){
  constexpr CGT cg = real_cg(l1,l2,L);
  #pragma unroll
  for (int i=0;i<2*l1+1;++i)
  #pragma unroll
  for (int j=0;j<2*l2+1;++j)
  #pragma unroll
  for (int m=0;m<2*L+1;++m){
    float c = cg.v[i][j][m];
    if (c != 0.0f) g[L*L+m] += c * f1[l1*l1+i] * f2[l2*l2+j];
  }
}

#define FOR_ALL_CG(X) \
  X(0,0,0) X(0,1,1) X(1,0,1) X(0,2,2) X(2,0,2) X(0,3,3) X(3,0,3) \
  X(1,1,0) X(1,1,1) X(1,1,2) \
  X(1,2,1) X(1,2,2) X(1,2,3) X(2,1,1) X(2,1,2) X(2,1,3) \
  X(1,3,2) X(1,3,3) X(3,1,2) X(3,1,3) \
  X(2,2,0) X(2,2,1) X(2,2,2) X(2,2,3) \
  X(2,3,1) X(2,3,2) X(2,3,3) X(3,2,1) X(3,2,2) X(3,2,3) \
  X(3,3,0) X(3,3,1) X(3,3,2) X(3,3,3)

__device__ __forceinline__ void all_contract(const float* __restrict__ f1,
                                             const float* __restrict__ f2,
                                             float* __restrict__ g){
#define XCG(a,b,c) cg_contract<a,b,c>(f1, f2, g);
  FOR_ALL_CG(XCG)
#undef XCG
}

// ---------------- geometry ----------------
__device__ __forceinline__ void compute_sh(float x, float y, float z, float* sh){
  sh[0]  = 0.28209479177387814f;
  sh[1]  = 0.4886025119029199f*y;
  sh[2]  = 0.4886025119029199f*z;
  sh[3]  = 0.4886025119029199f*x;
  sh[4]  = 1.0925484305920792f*x*y;
  sh[5]  = 1.0925484305920792f*y*z;
  sh[6]  = 0.31539156525252005f*(3.0f*z*z-1.0f);
  sh[7]  = 1.0925484305920792f*x*z;
  sh[8]  = 0.5462742152960396f*(x*x-y*y);
  sh[9]  = 0.5900435899266435f*y*(3.0f*x*x-y*y);
  sh[10] = 2.890611442640554f*x*y*z;
  sh[11] = 0.4570457994644658f*y*(5.0f*z*z-1.0f);
  sh[12] = 0.3731763325901154f*z*(5.0f*z*z-3.0f);
  sh[13] = 0.4570457994644658f*x*(5.0f*z*z-1.0f);
  sh[14] = 1.445305721320277f*z*(x*x-y*y);
  sh[15] = 0.5900435899266435f*x*(x*x-3.0f*y*y);
}

// ---------------- CSR build with distance filter ----------------
__global__ __launch_bounds__(256) void k_hist_d(
    const float* __restrict__ pos, const int* __restrict__ senders,
    const int* __restrict__ recv, int* __restrict__ counts, int E)
{
  int e = blockIdx.x*256 + threadIdx.x;
  if (e >= E) return;
  int s = senders[e], r = recv[e];
  float dx = pos[r*3+0]-pos[s*3+0];
  float dy = pos[r*3+1]-pos[s*3+1];
  float dz = pos[r*3+2]-pos[s*3+2];
  float d  = sqrtf(dx*dx+dy*dy+dz*dz + 1e-12f);
  if (d < RCUT) atomicAdd(&counts[r], 1);
}

__global__ __launch_bounds__(256) void k_scan1(const int* __restrict__ counts,
                                               int* __restrict__ offsets,
                                               int* __restrict__ bsum, int N){
  __shared__ int buf[256];
  int i = blockIdx.x*256 + threadIdx.x;
  int v = (i<N)? counts[i] : 0;
  buf[threadIdx.x] = v;
  __syncthreads();
  #pragma unroll
  for (int o=1;o<256;o<<=1){
    int t = (threadIdx.x>=o)? buf[threadIdx.x-o] : 0;
    __syncthreads();
    buf[threadIdx.x] += t;
    __syncthreads();
  }
  if (i<N) offsets[i] = buf[threadIdx.x] - v;      // local exclusive
  if (threadIdx.x==255) bsum[blockIdx.x] = buf[255];
}

__global__ __launch_bounds__(256) void k_scan2(const int* __restrict__ bsum,
                                               int* __restrict__ bbase, int SB){
  __shared__ int buf[256];
  int v = (threadIdx.x<SB)? bsum[threadIdx.x] : 0;
  buf[threadIdx.x] = v;
  __syncthreads();
  #pragma unroll
  for (int o=1;o<256;o<<=1){
    int t = (threadIdx.x>=o)? buf[threadIdx.x-o] : 0;
    __syncthreads();
    buf[threadIdx.x] += t;
    __syncthreads();
  }
  if (threadIdx.x<SB) bbase[threadIdx.x] = buf[threadIdx.x] - v;
}

__global__ __launch_bounds__(256) void k_scan3(int* __restrict__ offsets,
                                               const int* __restrict__ bbase, int N){
  int i = blockIdx.x*256 + threadIdx.x;
  if (i<N) offsets[i] += bbase[blockIdx.x];
}

// thread per edge: filter, claim slot, precompute geometry into bucket-ordered arrays
__global__ __launch_bounds__(256) void k_geom(
    const float* __restrict__ pos, const float* __restrict__ Winv,
    const int* __restrict__ species,
    const int* __restrict__ senders, const int* __restrict__ recv,
    const int* __restrict__ offsets, int* __restrict__ cursor,
    int* __restrict__ bucket_s, float* __restrict__ geomArr, int E)
{
  int e = blockIdx.x*256 + threadIdx.x;
  if (e >= E) return;
  int s = senders[e], r = recv[e];
  float dx = pos[r*3+0]-pos[s*3+0];
  float dy = pos[r*3+1]-pos[s*3+1];
  float dz = pos[r*3+2]-pos[s*3+2];
  float d  = sqrtf(dx*dx+dy*dy+dz*dz + 1e-12f);
  if (d >= RCUT) return;
  int p = atomicAdd(&cursor[r], 1);
  int slot = offsets[r] + p;
  float inv_d = 1.0f/d;
  float sh[16];
  compute_sh(dx*inv_d, dy*inv_d, dz*inv_d, sh);
  float fc = 0.5f*(cosf(d*(3.14159265358979323846f/RCUT))+1.0f);
  float b[8];
  #pragma unroll
  for (int q=0;q<NB;++q){
    float t = (d - (float)((double)q*(5.0/7.0))) * 1.6f;  // sigma=0.625
    b[q] = expf(-0.5f*t*t)*fc;
  }
  float* g = geomArr + (size_t)slot*GSTRIDE;
  #pragma unroll
  for (int i=0;i<16;++i) g[i] = sh[i];
  #pragma unroll
  for (int q=0;q<8;++q) g[16+q] = b[q];
  #pragma unroll
  for (int l=0;l<4;++l)
    #pragma unroll
    for (int n=0;n<4;++n){
      float acc=0.0f;
      #pragma unroll
      for (int q=0;q<NB;++q) acc += b[q]*Winv[l*32+q*4+n];
      g[24+l*4+n] = acc;
    }
  bucket_s[slot] = s | (species[s]<<16);
}

// ---------------- kernel A: gather pass-1 + tensor product + embed ----------------
__global__ __launch_bounds__(256) void kA_gather_tp(
    const float* __restrict__ emb, const int* __restrict__ species,
    const int* __restrict__ offsets, const int* __restrict__ counts,
    const int* __restrict__ bucket_s, const float* __restrict__ geomArr,
    float* __restrict__ feats, int N)
{
  int wv = threadIdx.x>>6;
  int r = blockIdx.x*4 + wv;
  if (r >= N) return;
  int lane = threadIdx.x & 63;
  int n = lane>>4, c = lane&15;
  int off = offsets[r], cnt = counts[r];
  float f[16];
  #pragma unroll
  for (int lm=0; lm<16; ++lm) f[lm]=0.0f;
  int pk = (cnt>0)? bucket_s[off] : 0;
  for (int j=0; j<cnt; ++j){
    int spec = pk>>16;
    if (j+1<cnt) pk = bucket_s[off+j+1];
    const float* gm = geomArr + (size_t)(off+j)*GSTRIDE;
    float e5 = 0.5f*emb[spec*NCH+c];                 // MP_SCALING
    float4 s0 = *(const float4*)(gm+0);
    float4 s1 = *(const float4*)(gm+4);
    float4 s2 = *(const float4*)(gm+8);
    float4 s3 = *(const float4*)(gm+12);
    float t0 = gm[24+0+n]*e5;
    float t1 = gm[24+4+n]*e5;
    float t2 = gm[24+8+n]*e5;
    float t3 = gm[24+12+n]*e5;
    f[0] += s0.x*t0;
    f[1] += s0.y*t1;  f[2] += s0.z*t1;  f[3] += s0.w*t1;
    f[4] += s1.x*t2;  f[5] += s1.y*t2;  f[6] += s1.z*t2;  f[7] += s1.w*t2;  f[8] += s2.x*t2;
    f[9] += s2.y*t3;  f[10]+= s2.z*t3;  f[11]+= s2.w*t3;
    f[12]+= s3.x*t3;  f[13]+= s3.y*t3;  f[14]+= s3.z*t3;  f[15]+= s3.w*t3;
  }
  float g[16];
  #pragma unroll
  for (int lm=0; lm<16; ++lm) g[lm]=f[lm];
  all_contract(f, f, g);
  float ek = emb[species[r]*NCH + c];
  float* fp = feats + (size_t)r*(LMDIM*KDIM) + lane;
  #pragma unroll
  for (int lm=0; lm<16; ++lm) fp[lm*KDIM] = g[lm]*ek;
}

// ---------------- kernel B: gather pass-2 + invariants + MLP ----------------
template<int l>
__device__ __forceinline__ float inv_term(const float* m){
  constexpr CGT cg = real_cg(l,l,0);
  float a=0.0f;
  #pragma unroll
  for (int i=0;i<2*l+1;++i)
  #pragma unroll
  for (int j=0;j<2*l+1;++j){
    float c = cg.v[i][j][0];
    if (c != 0.0f) a += c*m[l*l+i]*m[l*l+j];
  }
  return a;
}

__global__ __launch_bounds__(256) void kB_mp2_mlp(
    const float* __restrict__ Weq,
    const float* __restrict__ W1, const float* __restrict__ W2,
    const float* __restrict__ wl,
    const int* __restrict__ offsets, const int* __restrict__ counts,
    const int* __restrict__ bucket_s, const float* __restrict__ geomArr,
    const float* __restrict__ embedded, float* __restrict__ eatom, int N)
{
  __shared__ __align__(16) float Ash[4][256];
  int wv = threadIdx.x>>6;
  int r = blockIdx.x*4 + wv;
  if (r >= N) return;
  int k = threadIdx.x & 63;
  int off = offsets[r], cnt = counts[r];
  float* Arow = Ash[wv];
  float m[16];
  #pragma unroll
  for (int i=0;i<16;++i) m[i]=0.0f;

  int pk = (cnt>0)? bucket_s[off] : 0;
  for (int j=0; j<cnt; ++j){
    int s = pk & 0xFFFF;
    if (j+1<cnt) pk = bucket_s[off+j+1];
    // issue nb gathers first (the only pointer-chased loads)
    const float* npp = embedded + (size_t)s*(LMDIM*KDIM) + k;
    float nb[16];
    #pragma unroll
    for (int lm=0; lm<16; ++lm) nb[lm]=npp[lm*KDIM];
    const float* gm = geomArr + (size_t)(off+j)*GSTRIDE;
    float4 s0 = *(const float4*)(gm+0);
    float4 s1 = *(const float4*)(gm+4);
    float4 s2 = *(const float4*)(gm+8);
    float4 s3 = *(const float4*)(gm+12);
    float4 b0 = *(const float4*)(gm+16);
    float4 b1 = *(const float4*)(gm+20);
    float sh[16] = {s0.x,s0.y,s0.z,s0.w, s1.x,s1.y,s1.z,s1.w,
                    s2.x,s2.y,s2.z,s2.w, s3.x,s3.y,s3.z,s3.w};
    float b[8] = {b0.x,b0.y,b0.z,b0.w, b1.x,b1.y,b1.z,b1.w};
    float Req[4];
    #pragma unroll
    for (int L=0;L<4;++L){
      float acc=0.0f;
      #pragma unroll
      for (int q=0;q<NB;++q) acc += b[q]*Weq[L*(NB*KDIM) + q*KDIM + k];
      Req[L]=acc;
    }
    // cooperative A build: lane k computes entries k,64+k,128+k,192+k
    #pragma unroll
    for (int q=0;q<4;++q){
      int ent = q*64 + k;
      const float4* c4 = (const float4*)CFLAT.v[ent];
      float4 c0=c4[0], c1=c4[1], c2=c4[2], c3=c4[3];
      float acc = c0.x*sh[0]+c0.y*sh[1]+c0.z*sh[2]+c0.w*sh[3]
                + c1.x*sh[4]+c1.y*sh[5]+c1.z*sh[6]+c1.w*sh[7]
                + c2.x*sh[8]+c2.y*sh[9]+c2.z*sh[10]+c2.w*sh[11]
                + c3.x*sh[12]+c3.y*sh[13]+c3.z*sh[14]+c3.w*sh[15];
      Arow[ent] = acc;
    }
    // same-wave LDS RAW -> compiler lgkmcnt
    #pragma unroll
    for (int M=0;M<16;++M){
      const int L = (M==0)?0 : (M<4)?1 : (M<9)?2 : 3;
      const float4* a4 = (const float4*)(Arow + M*16);
      float4 a0=a4[0], a1=a4[1], a2=a4[2], a3=a4[3];
      float acc = a0.x*nb[0]+a0.y*nb[1]+a0.z*nb[2]+a0.w*nb[3]
                + a1.x*nb[4]+a1.y*nb[5]+a1.z*nb[6]+a1.w*nb[7]
                + a2.x*nb[8]+a2.y*nb[9]+a2.z*nb[10]+a2.w*nb[11]
                + a3.x*nb[12]+a3.y*nb[13]+a3.z*nb[14]+a3.w*nb[15];
      m[M] += acc*Req[L];
    }
  }

  // invariants (0.5 MP_SCALING already folded into CFLAT -> m)
  float inv = m[0];
  inv += inv_term<0>(m);
  inv += inv_term<1>(m);
  inv += inv_term<2>(m);
  inv += inv_term<3>(m);
  // per-wave MLP via LDS broadcast (reuse Arow)
  Arow[k] = inv;
  float a=0.0f;
  #pragma unroll
  for (int c=0;c<64;++c) a += Arow[c]*W1[c*64+k];
  a = a / (1.0f + expf(-a));           // silu
  Arow[64+k] = a;
  float h2=0.0f;
  #pragma unroll
  for (int c=0;c<64;++c) h2 += Arow[64+c]*W2[c*64+k];
  h2 = h2 / (1.0f + expf(-h2));
  float e = h2*wl[k];
  #pragma unroll
  for (int o=32; o>0; o>>=1) e += __shfl_down(e, o);
  if (k==0) eatom[r] = e;
}

__global__ __launch_bounds__(256) void k_reduce(const float* __restrict__ eatom,
                                                float* __restrict__ out, int N){
  __shared__ float buf[256];
  float a=0.0f;
  for (int i=threadIdx.x; i<N; i+=256) a += eatom[i];
  buf[threadIdx.x]=a;
  __syncthreads();
  #pragma unroll
  for (int o=128;o>0;o>>=1){
    if (threadIdx.x<o) buf[threadIdx.x]+=buf[threadIdx.x+o];
    __syncthreads();
  }
  if (threadIdx.x==0) out[0]=buf[0];
}

// ---------------- launch ----------------
extern "C" void kernel_launch(void* const* d_in, const int* in_sizes, int n_in,
                              void* d_out, int out_size, void* d_ws, size_t ws_size,
                              hipStream_t stream)
{
  const float* pos     = (const float*)d_in[0];
  const float* emb     = (const float*)d_in[1];
  const float* Winv    = (const float*)d_in[2];
  const float* Weq     = (const float*)d_in[3];
  const float* W1      = (const float*)d_in[4];
  const float* W2      = (const float*)d_in[5];
  const float* wl      = (const float*)d_in[6];
  const int*   species = (const int*)d_in[7];
  const int*   senders = (const int*)d_in[8];
  const int*   recv    = (const int*)d_in[9];
  int N = in_sizes[7];
  int E = in_sizes[8];

  char* ws = (char*)d_ws;
  float* feats   = (float*)ws;                                   // N*1024 f32
  float* geomArr = feats + (size_t)N*(LMDIM*KDIM);               // E*GSTRIDE f32 (worst case)
  float* eatom   = geomArr + (size_t)E*GSTRIDE;                  // N f32
  int*   counts  = (int*)(eatom + N);                            // N
  int*   cursor  = counts + N;                                   // N
  int*   offsets = cursor + N;                                   // N
  int*   bsum    = offsets + N;                                  // 256
  int*   bbase   = bsum + 256;                                   // 256
  int*   bucket_s= bbase + 256;                                  // E

  hipMemsetAsync(counts, 0, 2*(size_t)N*sizeof(int), stream);    // counts+cursor

  int ebl = (E+255)/256;
  int abl = (N+3)/4;
  int SB  = (N+255)/256;
  k_hist_d<<<ebl, 256, 0, stream>>>(pos, senders, recv, counts, E);
  k_scan1<<<SB, 256, 0, stream>>>(counts, offsets, bsum, N);
  k_scan2<<<1, 256, 0, stream>>>(bsum, bbase, SB);
  k_scan3<<<SB, 256, 0, stream>>>(offsets, bbase, N);
  k_geom<<<ebl, 256, 0, stream>>>(pos, Winv, species, senders, recv, offsets, cursor,
                                  bucket_s, geomArr, E);
  kA_gather_tp<<<abl, 256, 0, stream>>>(emb, species, offsets, counts, bucket_s, geomArr, feats, N);
  kB_mp2_mlp<<<abl, 256, 0, stream>>>(Weq, W1, W2, wl, offsets, counts, bucket_s, geomArr,
                                      feats, eatom, N);
  k_reduce<<<1, 256, 0, stream>>>(eatom, (float*)d_out, N);
}